// Round 7
// baseline (975.373 us; speedup 1.0000x reference)
//
#include <hip/hip_runtime.h>

typedef __attribute__((ext_vector_type(8))) short short8;
typedef __attribute__((ext_vector_type(4))) short short4v;
typedef __attribute__((ext_vector_type(4))) float floatx4;

__device__ inline short f2bf(float v) {
    unsigned u = __builtin_bit_cast(unsigned, v);
    unsigned r = (u + 0x7fffu + ((u >> 16) & 1u)) >> 16;
    return (short)r;
}
__device__ inline float bf2f(short s) {
    unsigned u = ((unsigned)(unsigned short)s) << 16;
    return __builtin_bit_cast(float, u);
}
__device__ inline short4v pack4(float4 v) {
    short4v o;
    o[0] = f2bf(v.x); o[1] = f2bf(v.y); o[2] = f2bf(v.z); o[3] = f2bf(v.w);
    return o;
}
__device__ inline short4v silu4(float4 v) {
    float4 s;
    s.x = v.x / (1.f + __expf(-v.x));
    s.y = v.y / (1.f + __expf(-v.y));
    s.z = v.z / (1.f + __expf(-v.z));
    s.w = v.w / (1.f + __expf(-v.w));
    return pack4(s);
}

// spline weights for value v: 8 kept bases of the uniform cubic B-spline
__device__ inline void spline8(float v, short* arr) {
    float u = (v + 2.2f) * 2.5f;
    float fj = floorf(u);
    int jj = (int)fj;
    float t1 = u - fj;
    float ok = (jj >= 0 && jj <= 10) ? (1.f / 6.f) : 0.f;
    float t2 = t1 * t1, t3 = t2 * t1;
    float omt = 1.f - t1;
    short sw0 = f2bf(omt * omt * omt * ok);
    short sw1 = f2bf((3.f * t3 - 6.f * t2 + 4.f) * ok);
    short sw2 = f2bf((-3.f * t3 + 3.f * t2 + 3.f * t1 + 1.f) * ok);
    short sw3 = f2bf(t3 * ok);
#pragma unroll
    for (int s = 0; s < 8; ++s) {
        int rr = s - jj + 3;
        arr[s] = (rr == 0) ? sw0 : (rr == 1) ? sw1 : (rr == 2) ? sw2
                 : (rr == 3) ? sw3 : (short)0;
    }
}
__device__ inline void expand4(float4 v, short* silu_dst, short* spl_dst) {
    *(short4v*)silu_dst = silu4(v);
    short arr[8];
    spline8(v.x, arr); *(short8*)(spl_dst)      = *(const short8*)arr;
    spline8(v.y, arr); *(short8*)(spl_dst + 8)  = *(const short8*)arr;
    spline8(v.z, arr); *(short8*)(spl_dst + 16) = *(const short8*)arr;
    spline8(v.w, arr); *(short8*)(spl_dst + 24) = *(const short8*)arr;
}

// ---------------------------------------------------------------------------
// gemm128w: 128x128 tile, BK=64, 4 waves. A via global_load_lds + 8-slot XOR
// swizzle (r3-proven, 0 conflicts). W DIRECT global->VGPR (no LDS): the
// B-fragment pattern (16 rows x 16B, same 16B column chunk) is already
// coalesced; identical L2 addresses to staging, but halves LDS write traffic
// and removes W ds_reads. r6 post-mortem: staging rate was schedule-invariant
// at ~911cy/16KB-slot == LDS port saturation (writes 96KB + reads 192KB per
// CU-slot at 128/256 B/cy). With W out of LDS: ~375cy LDS, ~480cy MFMA.
// LDS 16KB -> 4 blocks/CU co-resident (grid 768 fully resident), TLP hides
// W-load latency. Math bitwise-identical to r3. Split-K fp32 partials.
// ---------------------------------------------------------------------------
__global__ __launch_bounds__(256, 4) void gemm128w(
    int S, int Kh,
    const short* __restrict__ A0, int lda0, long sA0, int K0,
    const short* __restrict__ W0, int ldw0, long sW0,
    const short* __restrict__ A1, int lda1, long sA1,
    const short* __restrict__ W1, int ldw1, long sW1,
    float* __restrict__ C, int ldc, long sC, long sSplit)
{
    __shared__ short As[128 * 64];
    const int t = threadIdx.x;
    // XCD remap; grid must be (32,4,Z)
    int n = blockIdx.x + (blockIdx.y << 5) + (blockIdx.z << 7);
    int k8 = n & 7, j = n >> 3;
    int byi = j & 3;
    int t2 = j >> 2;
    int bxi = k8 * 4 + (t2 & 3);
    int bzi = t2 >> 2;
    const int z = bzi / S, s = bzi % S;
    const int bm = bxi * 128, bn = byi * 128;
    const int lane = t & 63, w = t >> 6;
    const int wm = (w >> 1) * 64, wn = (w & 1) * 64;
    const int lrow = lane & 15, quad = lane >> 4;

    floatx4 acc[4][4] = {};

    const int kbeg = s * Kh, kend = kbeg + Kh;

    const short* A = A0 + (long)z * sA0;
    const short* W = W0 + (long)z * sW0;
    int lda = lda0, ldw = ldw0;
    int kb = kbeg, ke = (kend < K0) ? kend : K0;   // seg0 window

    for (int seg = 0; seg < 2; ++seg) {
        // per-wave W row base for this segment (rows bn+wn+ni*16+lrow)
        const short* Wb0 = W + (long)(bn + wn + lrow) * ldw;
        for (int kv = kb; kv < ke; kv += 64) {
#pragma unroll
            for (int i = 0; i < 4; ++i) {          // A: 128 rows x 8 chunks
                int c = i * 256 + t;
                int row = c >> 3;
                int cg = ((c ^ row) & 7) * 8;      // pre-swizzled source chunk
                const short* gp = A + (long)(bm + row) * lda + kv + cg;
                __builtin_amdgcn_global_load_lds(
                    (const __attribute__((address_space(1))) void*)gp,
                    (__attribute__((address_space(3))) void*)(As + c * 8), 16, 0, 0);
            }
            // issue W fragment loads (global->VGPR, no barrier dependency)
            short8 bfr[2][4];
#pragma unroll
            for (int kk = 0; kk < 2; ++kk)
#pragma unroll
                for (int ni = 0; ni < 4; ++ni)
                    bfr[kk][ni] = *(const short8*)(
                        Wb0 + (long)ni * 16 * ldw + kv + (kk * 4 + quad) * 8);
            __syncthreads();
#pragma unroll
            for (int kk = 0; kk < 2; ++kk) {
                short8 af[4];
#pragma unroll
                for (int mi = 0; mi < 4; ++mi) {
                    int r = wm + mi * 16 + lrow;
                    af[mi] = *(const short8*)(As + r * 64 +
                                              (((kk * 4 + quad) ^ (r & 7)) * 8));
                }
#pragma unroll
                for (int mi = 0; mi < 4; ++mi)
#pragma unroll
                    for (int ni = 0; ni < 4; ++ni)
                        acc[mi][ni] = __builtin_amdgcn_mfma_f32_16x16x32_bf16(
                            af[mi], bfr[kk][ni], acc[mi][ni], 0, 0, 0);
            }
            __syncthreads();
        }
        // segment-1 window (empty loop if this split doesn't reach seg1)
        A = A1 + (long)z * sA1;
        W = W1 + (long)z * sW1;
        lda = lda1; ldw = ldw1;
        kb = ((kbeg > K0) ? kbeg : K0) - K0;
        ke = kend - K0;
    }

    float* Cz = C + (long)z * sC + (long)s * sSplit;
#pragma unroll
    for (int mi = 0; mi < 4; ++mi)
#pragma unroll
        for (int ni = 0; ni < 4; ++ni)
#pragma unroll
            for (int r = 0; r < 4; ++r) {
                int row = bm + wm + mi * 16 + quad * 4 + r;
                int col = bn + wn + ni * 16 + lrow;
                Cz[(long)row * ldc + col] = acc[mi][ni][r];
            }
}

// ---------------------------------------------------------------------------
// gemm64w: small GEMMs (gates, ogate). 64x128 tile, BK=64, A-LDS + W-direct
// (same halved-LDS scheme as gemm128w). bf16 out.
// ---------------------------------------------------------------------------
__global__ __launch_bounds__(256, 4) void gemm64w(
    const short* __restrict__ A0, int lda0, long sA0, int K0,
    const short* __restrict__ W0, int ldw0, long sW0,
    short* __restrict__ C, int ldc, long sC)
{
    __shared__ short As[64 * 64];
    const int t = threadIdx.x;
    const int z = blockIdx.z;
    const int bm = blockIdx.x * 64;
    const int bn = blockIdx.y * 128;
    const int lane = t & 63, w = t >> 6;
    const int wm = (w >> 1) * 32, wn = (w & 1) * 64;
    const int lrow = lane & 15, quad = lane >> 4;

    floatx4 acc[2][4] = {};

    const short* A = A0 + (long)z * sA0;
    const short* W = W0 + (long)z * sW0;
    const short* Wb0 = W + (long)(bn + wn + lrow) * ldw0;

    for (int k0 = 0; k0 < K0; k0 += 64) {
#pragma unroll
        for (int i = 0; i < 2; ++i) {      // A: 64 rows x 8 chunks = 512
            int c = i * 256 + t;
            int row = c >> 3;
            int cg = ((c ^ row) & 7) * 8;
            const short* gp = A + (long)(bm + row) * lda0 + k0 + cg;
            __builtin_amdgcn_global_load_lds(
                (const __attribute__((address_space(1))) void*)gp,
                (__attribute__((address_space(3))) void*)(As + c * 8), 16, 0, 0);
        }
        short8 bfr[2][4];
#pragma unroll
        for (int kk = 0; kk < 2; ++kk)
#pragma unroll
            for (int ni = 0; ni < 4; ++ni)
                bfr[kk][ni] = *(const short8*)(
                    Wb0 + (long)ni * 16 * ldw0 + k0 + (kk * 4 + quad) * 8);
        __syncthreads();
#pragma unroll
        for (int kk = 0; kk < 2; ++kk) {
            short8 af[2];
#pragma unroll
            for (int mi = 0; mi < 2; ++mi) {
                int r = wm + mi * 16 + lrow;
                af[mi] = *(const short8*)(As + r * 64 +
                                          (((kk * 4 + quad) ^ (r & 7)) * 8));
            }
#pragma unroll
            for (int mi = 0; mi < 2; ++mi)
#pragma unroll
                for (int ni = 0; ni < 4; ++ni)
                    acc[mi][ni] = __builtin_amdgcn_mfma_f32_16x16x32_bf16(
                        af[mi], bfr[kk][ni], acc[mi][ni], 0, 0, 0);
        }
        __syncthreads();
    }

    short* Cz = C + (long)z * sC;
#pragma unroll
    for (int mi = 0; mi < 2; ++mi)
#pragma unroll
        for (int ni = 0; ni < 4; ++ni)
#pragma unroll
            for (int r = 0; r < 4; ++r) {
                int row = bm + wm + mi * 16 + quad * 4 + r;
                int col = bn + wn + ni * 16 + lrow;
                Cz[(long)row * ldc + col] = f2bf(acc[mi][ni][r]);
            }
}

// ---------------------------------------------------------------------------
// megapack8: all weight fp32->bf16 packs, 8 elems/thread. grid 13440 x 256
// ---------------------------------------------------------------------------
__global__ __launch_bounds__(256) void megapack8(
    const float* __restrict__ wx_b, const float* __restrict__ wx_s,
    const float* __restrict__ wh_b, const float* __restrict__ wh_s,
    const float* __restrict__ hz_b, const float* __restrict__ hz_s,
    const float* __restrict__ phi_b, const float* __restrict__ phi_s,
    const float* __restrict__ hh_w, const float* __restrict__ o_w,
    const float* __restrict__ f_w, const float* __restrict__ i_w,
    const float* __restrict__ g_w,
    short* __restrict__ Wx, short* __restrict__ Wh, short* __restrict__ Whz,
    short* __restrict__ Wphi, short* __restrict__ HHb, short* __restrict__ OWb,
    short* __restrict__ Wg)
{
    int bid = blockIdx.x, tid = threadIdx.x;
    const float* sp;
    short* dst;
    long e;
    if (bid < 1728) {                        // Wx: (1536, 2304) kan-pack
        e = ((long)bid * 256 + tid) * 8;
        int r = (int)(e / 2304), c = (int)(e % 2304);
        sp = (c < 256) ? wx_b + (long)r * 256 + c
                       : wx_s + (long)r * 2048 + (c - 256);
        dst = Wx + e;
    } else if (bid < 12096) {                // Wh/Whz/Wphi: (1536, 4608) each
        int jb = bid - 1728;
        int job = jb / 3456, lb = jb % 3456;
        const float* bp = (job == 0) ? wh_b : (job == 1) ? hz_b : phi_b;
        const float* spw = (job == 0) ? wh_s : (job == 1) ? hz_s : phi_s;
        short* dp = (job == 0) ? Wh : (job == 1) ? Whz : Wphi;
        e = ((long)lb * 256 + tid) * 8;
        int r = (int)(e / 4608), c = (int)(e % 4608);
        sp = (c < 512) ? bp + (long)r * 512 + c
                       : spw + (long)r * 4096 + (c - 512);
        dst = dp + e;
    } else if (bid < 12480) {                // hh_w flat 786432
        e = ((long)(bid - 12096) * 256 + tid) * 8;
        sp = hh_w + e; dst = HHb + e;
    } else if (bid < 12864) {                // o_w flat 786432
        e = ((long)(bid - 12480) * 256 + tid) * 8;
        sp = o_w + e; dst = OWb + e;
    } else if (bid < 13056) {                // f_w flat 393216
        e = ((long)(bid - 12864) * 256 + tid) * 8;
        sp = f_w + e; dst = Wg + e;
    } else if (bid < 13248) {                // i_w
        e = ((long)(bid - 13056) * 256 + tid) * 8;
        sp = i_w + e; dst = Wg + 393216 + e;
    } else {                                 // g_w
        e = ((long)(bid - 13248) * 256 + tid) * 8;
        sp = g_w + e; dst = Wg + 786432 + e;
    }
    float4 a = *(const float4*)sp;
    float4 b = *(const float4*)(sp + 4);
    short8 o;
    o[0] = f2bf(a.x); o[1] = f2bf(a.y); o[2] = f2bf(a.z); o[3] = f2bf(a.w);
    o[4] = f2bf(b.x); o[5] = f2bf(b.y); o[6] = f2bf(b.z); o[7] = f2bf(b.w);
    *(short8*)dst = o;
}

// ---------------------------------------------------------------------------
// prep_acts4: 4 elems/thread. grid: 9216 blocks x 256
// ---------------------------------------------------------------------------
__global__ __launch_bounds__(256) void prep_acts4(
    const float* __restrict__ x_t, const float* __restrict__ h_prev,
    const float* __restrict__ z_prev,
    short* __restrict__ Xe, short* __restrict__ Agate,
    short* __restrict__ Ze, short* __restrict__ zraw)
{
    int bid = blockIdx.x, tid = threadIdx.x;
    if (bid < 1024) {                        // x: 4 rows/block, 64 thr/row
        int r = (bid << 2) + (tid >> 6);
        int i = (tid & 63) << 2;
        float4 v = *(const float4*)(x_t + (long)r * 256 + i);
        *(short4v*)(Agate + (long)r * 768 + i) = pack4(v);
        long ob = (long)r * 2304;
        expand4(v, Xe + ob + i, Xe + ob + 256 + (long)i * 8);
    } else if (bid < 3072) {                 // h cast: flat
        long idx = ((long)(bid - 1024) * 256 + tid) * 4;
        float4 v = *(const float4*)(h_prev + idx);
        long b = idx >> 9; int hh = (int)(idx & 511);
        *(short4v*)(Agate + b * 768 + 256 + hh) = pack4(v);
    } else {                                 // z: 2 rows/block, 128 thr/row
        int jz = bid - 3072;
        int r = (jz << 1) + (tid >> 7);
        int i = (tid & 127) << 2;
        float4 v = *(const float4*)(z_prev + (long)r * 512 + i);
        *(short4v*)(zraw + (long)r * 512 + i) = pack4(v);
        long ob = (long)r * 4608;
        expand4(v, Ze + ob + i, Ze + ob + 512 + (long)i * 8);
    }
}

// ---------------------------------------------------------------------------
// expand_pair4: v = sum_s P[idx + s*sSplit]; silu+spline expand; optional
// bf16 compact. 4 elems/thread, 2 rows/block. grid: 6144 blocks x 256
// ---------------------------------------------------------------------------
__global__ __launch_bounds__(256) void expand_pair4(
    const float* __restrict__ P, long sSplit, int S,
    short* __restrict__ out, short* __restrict__ compact)
{
    int tid = threadIdx.x;
    int r = (blockIdx.x << 1) + (tid >> 7);
    int i = (tid & 127) << 2;
    long idx = (long)r * 512 + i;
    float4 v = *(const float4*)(P + idx);
    for (int s = 1; s < S; ++s) {
        float4 a = *(const float4*)(P + idx + (long)s * sSplit);
        v.x += a.x; v.y += a.y; v.z += a.z; v.w += a.w;
    }
    if (compact) *(short4v*)(compact + idx) = pack4(v);
    long ob = (long)r * 4608;
    expand4(v, out + ob + i, out + ob + 512 + (long)i * 8);
}

// ---------------------------------------------------------------------------
// ln_wave: LayerNorm rows of 512, one wave per row. grid: 3072 x 256
// ---------------------------------------------------------------------------
__global__ __launch_bounds__(256) void ln_wave(const float* __restrict__ P,
                                               long sSplit, int S,
                                               const float* __restrict__ hh_b,
                                               const float* __restrict__ ln_g,
                                               const float* __restrict__ ln_b,
                                               float* __restrict__ out)
{
    int wv = threadIdx.x >> 6, lane = threadIdx.x & 63;
    int row = blockIdx.x * 4 + wv;           // [0, 12288)
    int l = row >> 12;
    int col = lane * 8;
    long base = (long)row * 512 + col;
    float v[8];
#pragma unroll
    for (int e = 0; e < 8; ++e) v[e] = hh_b[l * 512 + col + e];
    for (int s = 0; s < S; ++s) {
        float4 a = *(const float4*)(P + base + (long)s * sSplit);
        float4 b = *(const float4*)(P + base + 4 + (long)s * sSplit);
        v[0] += a.x; v[1] += a.y; v[2] += a.z; v[3] += a.w;
        v[4] += b.x; v[5] += b.y; v[6] += b.z; v[7] += b.w;
    }
    float sm = 0.f, sq = 0.f;
#pragma unroll
    for (int e = 0; e < 8; ++e) { sm += v[e]; sq += v[e] * v[e]; }
#pragma unroll
    for (int off = 32; off; off >>= 1) {
        sm += __shfl_down(sm, off);
        sq += __shfl_down(sq, off);
    }
    sm = __shfl(sm, 0);
    sq = __shfl(sq, 0);
    float mu = sm * (1.f / 512.f);
    float var = sq * (1.f / 512.f) - mu * mu;
    float rstd = rsqrtf(var + 1e-5f);
    float o[8];
#pragma unroll
    for (int e = 0; e < 8; ++e)
        o[e] = (v[e] - mu) * rstd * ln_g[l * 512 + col + e] + ln_b[l * 512 + col + e];
    float* op = out + base;
    *(float4*)op = make_float4(o[0], o[1], o[2], o[3]);
    *(float4*)(op + 4) = make_float4(o[4], o[5], o[6], o[7]);
}

// final LSTM-style cell epilogue -> h_t, c_t
__global__ __launch_bounds__(256) void cell_epilogue(const short* __restrict__ gates,
                                                     const short* __restrict__ opre,
                                                     const float* __restrict__ c_prev,
                                                     const float* __restrict__ f_b,
                                                     const float* __restrict__ i_b,
                                                     const float* __restrict__ g_b,
                                                     const float* __restrict__ o_b,
                                                     float* __restrict__ out)
{
    long idx = blockIdx.x * 256L + threadIdx.x;
    long b = idx >> 9; int h = (int)(idx & 511);
    const short* g = gates + b * 1536;
    float fp = bf2f(g[h]) + f_b[h];
    float ip = bf2f(g[512 + h]) + i_b[h];
    float gp = bf2f(g[1024 + h]) + g_b[h];
    float op = bf2f(opre[idx]) + o_b[h];
    float ft = 1.f / (1.f + __expf(-fp));
    float it = 1.f / (1.f + __expf(-ip));
    float gt = tanhf(gp);
    float ot = 1.f / (1.f + __expf(-op));
    float c = ft * c_prev[idx] + it * gt;
    out[idx] = ot * tanhf(c);
    out[idx + 2097152] = c;
}

// ---------------------------------------------------------------------------
extern "C" void kernel_launch(void* const* d_in, const int* in_sizes, int n_in,
                              void* d_out, int out_size, void* d_ws, size_t ws_size,
                              hipStream_t stream)
{
    const float* x_t       = (const float*)d_in[0];
    const float* h_prev    = (const float*)d_in[1];
    const float* c_prev    = (const float*)d_in[2];
    const float* z_prev    = (const float*)d_in[3];
    const float* wx_base   = (const float*)d_in[4];
    const float* wx_spline = (const float*)d_in[5];
    const float* wh_base   = (const float*)d_in[6];
    const float* wh_spline = (const float*)d_in[7];
    const float* hz_base   = (const float*)d_in[8];
    const float* hz_spline = (const float*)d_in[9];
    const float* phi_base  = (const float*)d_in[10];
    const float* phi_spline= (const float*)d_in[11];
    const float* hh_w      = (const float*)d_in[12];
    const float* hh_b      = (const float*)d_in[13];
    const float* ln_g      = (const float*)d_in[14];
    const float* ln_b      = (const float*)d_in[15];
    const float* f_w       = (const float*)d_in[16];
    const float* f_b       = (const float*)d_in[17];
    const float* i_w       = (const float*)d_in[18];
    const float* i_b       = (const float*)d_in[19];
    const float* g_w       = (const float*)d_in[20];
    const float* g_b       = (const float*)d_in[21];
    const float* o_w       = (const float*)d_in[22];
    const float* o_b       = (const float*)d_in[23];
    float* out = (float*)d_out;
    const long BH = 4096L * 512;

    char* p = (char*)d_ws;
    auto alloc = [&](size_t bytes) {
        char* q = p;
        p += (bytes + 255) & ~(size_t)255;
        return q;
    };

    short* Wx   = (short*)alloc(3L * 512 * 2304 * 2);
    short* Wh   = (short*)alloc(3L * 512 * 4608 * 2);
    short* Whz  = (short*)alloc(3L * 512 * 4608 * 2);
    short* Wphi = (short*)alloc(3L * 512 * 4608 * 2);
    short* HHb  = (short*)alloc(3L * 512 * 512 * 2);
    short* OWb  = (short*)alloc(512L * 1536 * 2);
    short* Wg   = (short*)alloc(1536L * 768 * 2);
    short* Agate= (short*)alloc(4096L * 768 * 2);
    short* zraw = (short*)alloc(3L * 4096 * 512 * 2);
    short* XR   = (short*)alloc(4096L * 2304 * 2);      // Xe, later Rbuf
    short* Ebuf = (short*)alloc(3L * 4096 * 4608 * 2);  // Ze -> Se -> Oe -> gbuf/opre

    const int S = 2;                                    // split-K factor
    const long PS = 3L * 4096 * 512;                    // elems per split
    float* Pbuf = (float*)alloc((size_t)S * PS * 4);    // fp32 partials

    short* Xe = XR;
    short* Rbuf = XR;
    short* gbuf = Ebuf;
    short* opre = Ebuf + 4096L * 1536;

    // ---- all weight packing in one launch ----
    megapack8<<<13440, 256, 0, stream>>>(
        wx_base, wx_spline, wh_base, wh_spline, hz_base, hz_spline,
        phi_base, phi_spline, hh_w, o_w, f_w, i_w, g_w,
        Wx, Wh, Whz, Wphi, HHb, OWb, Wg);

    // ---- all activation prep in one launch ----
    prep_acts4<<<9216, 256, 0, stream>>>(x_t, h_prev, z_prev, Xe, Agate, Ebuf, zraw);

    // ---- s = Xe @ Wx^T + Ze @ Wh^T  (Ktot=6912, split 3456/3456) ----
    gemm128w<<<dim3(32, 4, 3 * S), 256, 0, stream>>>(S, 3456,
        Xe, 2304, 0L, 2304,              Wx, 2304, 512L * 2304,
        Ebuf, 4608, 4096L * 4608,        Wh, 4608, 512L * 4608,
        Pbuf, 512, 4096L * 512, PS);

    // ---- Se = expand(sum P) ----
    expand_pair4<<<6144, 256, 0, stream>>>(Pbuf, PS, S, Ebuf, (short*)0);

    // ---- o = Se @ Wphi^T (Ktot=4608, split 2304/2304) -> fp32 partials ----
    gemm128w<<<dim3(32, 4, 3 * S), 256, 0, stream>>>(S, 2304,
        Ebuf, 4608, 4096L * 4608, 4608,  Wphi, 4608, 512L * 4608,
        Ebuf, 4608, 4096L * 4608,        Wphi, 4608, 512L * 4608,
        Pbuf, 1536, 512, PS);

    // ---- Oe = expand(sum P); compact bf16 -> Rbuf ----
    expand_pair4<<<6144, 256, 0, stream>>>(Pbuf, PS, S, Ebuf, Rbuf);

    // ---- zpre = Oe @ Whz^T + zraw @ hh_w^T (Ktot=5120, split 2560/2560) ----
    gemm128w<<<dim3(32, 4, 3 * S), 256, 0, stream>>>(S, 2560,
        Ebuf, 13824, 4608, 4608,         Whz, 4608, 512L * 4608,
        zraw, 512, 4096L * 512,          HHb, 512, 512L * 512,
        Pbuf, 512, 4096L * 512, PS);

    // ---- z_all = LN(sum P + hh_b) ----
    ln_wave<<<3072, 256, 0, stream>>>(Pbuf, PS, S, hh_b, ln_g, ln_b, out + 2 * BH);

    // ---- gates (f,i,g) pre-activations (bf16 out) ----
    gemm64w<<<dim3(64, 12, 1), 256, 0, stream>>>(
        Agate, 768, 0L, 768,  Wg, 768, 0L,
        gbuf, 1536, 0);

    // ---- output gate pre-activation (bf16 out) ----
    gemm64w<<<dim3(64, 4, 1), 256, 0, stream>>>(
        Rbuf, 1536, 0L, 1536, OWb, 1536, 0L,
        opre, 512, 0);

    // ---- h_t, c_t ----
    cell_epilogue<<<8192, 256, 0, stream>>>(gbuf, opre, c_prev, f_b, i_b, g_b, o_b, out);
}

// Round 8
// 704.241 us; speedup vs baseline: 1.3850x; 1.3850x over previous
//
#include <hip/hip_runtime.h>

typedef __attribute__((ext_vector_type(8))) short short8;
typedef __attribute__((ext_vector_type(4))) short short4v;
typedef __attribute__((ext_vector_type(4))) float floatx4;

__device__ inline short f2bf(float v) {
    unsigned u = __builtin_bit_cast(unsigned, v);
    unsigned r = (u + 0x7fffu + ((u >> 16) & 1u)) >> 16;
    return (short)r;
}
__device__ inline float bf2f(short s) {
    unsigned u = ((unsigned)(unsigned short)s) << 16;
    return __builtin_bit_cast(float, u);
}
__device__ inline short4v pack4(float4 v) {
    short4v o;
    o[0] = f2bf(v.x); o[1] = f2bf(v.y); o[2] = f2bf(v.z); o[3] = f2bf(v.w);
    return o;
}
__device__ inline short4v silu4(float4 v) {
    float4 s;
    s.x = v.x / (1.f + __expf(-v.x));
    s.y = v.y / (1.f + __expf(-v.y));
    s.z = v.z / (1.f + __expf(-v.z));
    s.w = v.w / (1.f + __expf(-v.w));
    return pack4(s);
}

// spline weights for value v: 8 kept bases of the uniform cubic B-spline
__device__ inline void spline8(float v, short* arr) {
    float u = (v + 2.2f) * 2.5f;
    float fj = floorf(u);
    int jj = (int)fj;
    float t1 = u - fj;
    float ok = (jj >= 0 && jj <= 10) ? (1.f / 6.f) : 0.f;
    float t2 = t1 * t1, t3 = t2 * t1;
    float omt = 1.f - t1;
    short sw0 = f2bf(omt * omt * omt * ok);
    short sw1 = f2bf((3.f * t3 - 6.f * t2 + 4.f) * ok);
    short sw2 = f2bf((-3.f * t3 + 3.f * t2 + 3.f * t1 + 1.f) * ok);
    short sw3 = f2bf(t3 * ok);
#pragma unroll
    for (int s = 0; s < 8; ++s) {
        int rr = s - jj + 3;
        arr[s] = (rr == 0) ? sw0 : (rr == 1) ? sw1 : (rr == 2) ? sw2
                 : (rr == 3) ? sw3 : (short)0;
    }
}
__device__ inline void expand4(float4 v, short* silu_dst, short* spl_dst) {
    *(short4v*)silu_dst = silu4(v);
    short arr[8];
    spline8(v.x, arr); *(short8*)(spl_dst)      = *(const short8*)arr;
    spline8(v.y, arr); *(short8*)(spl_dst + 8)  = *(const short8*)arr;
    spline8(v.z, arr); *(short8*)(spl_dst + 16) = *(const short8*)arr;
    spline8(v.w, arr); *(short8*)(spl_dst + 24) = *(const short8*)arr;
}

// ---------------------------------------------------------------------------
// gemm128o: 128x128 tile, BK=64, EIGHT waves (512 thr), wave-tile 32x64.
// Identical tile/LDS/swizzle/barrier structure to the r3-proven kernel
// (0 bank conflicts, ~123us); only the wave decomposition changes: per-wave
// work halves (16 MFMA, 6 ds_reads/kk, 2+2 staging loads/thread) and
// waves/SIMD doubles 3->6 (24 waves/CU at 3 blocks/CU, grid 768 exact).
// r7 post-mortem: nothing saturated (HBM 27%, L2 31%, MFMA 8.5%, conflicts
// 0) and per-step cost is schedule-invariant -> issue/latency-bound with
// too few waves to interleave. launch_bounds(512,6) caps VGPR at 85.
// Split-K over concatenated 2-segment K; fp32 partials at C + s*sSplit.
// ---------------------------------------------------------------------------
__global__ __launch_bounds__(512, 6) void gemm128o(
    int S, int Kh,
    const short* __restrict__ A0, int lda0, long sA0, int K0,
    const short* __restrict__ W0, int ldw0, long sW0,
    const short* __restrict__ A1, int lda1, long sA1,
    const short* __restrict__ W1, int ldw1, long sW1,
    float* __restrict__ C, int ldc, long sC, long sSplit)
{
    __shared__ short As[128 * 64];
    __shared__ short Ws[128 * 64];
    const int t = threadIdx.x;
    // XCD remap; grid must be (32,4,Z)
    int n = blockIdx.x + (blockIdx.y << 5) + (blockIdx.z << 7);
    int k8 = n & 7, j = n >> 3;
    int byi = j & 3;
    int t2 = j >> 2;
    int bxi = k8 * 4 + (t2 & 3);
    int bzi = t2 >> 2;
    const int z = bzi / S, s = bzi % S;
    const int bm = bxi * 128, bn = byi * 128;
    const int lane = t & 63, w = t >> 6;
    const int wm = (w >> 1) * 32, wn = (w & 1) * 64;   // 4 M-waves x 2 N-waves
    const int lrow = lane & 15, quad = lane >> 4;

    floatx4 acc[2][4] = {};

    const int kbeg = s * Kh, kend = kbeg + Kh;

    const short* A = A0 + (long)z * sA0;
    const short* W = W0 + (long)z * sW0;
    int lda = lda0, ldw = ldw0;
    int kb = kbeg, ke = (kend < K0) ? kend : K0;   // seg0 window

    for (int seg = 0; seg < 2; ++seg) {
        for (int kv = kb; kv < ke; kv += 64) {
#pragma unroll
            for (int i = 0; i < 2; ++i) {          // A,W: 128 rows x 8 chunks
                int c = i * 512 + t;
                int row = c >> 3;
                int cg = ((c ^ row) & 7) * 8;      // pre-swizzled source chunk
                const short* gp = A + (long)(bm + row) * lda + kv + cg;
                __builtin_amdgcn_global_load_lds(
                    (const __attribute__((address_space(1))) void*)gp,
                    (__attribute__((address_space(3))) void*)(As + c * 8), 16, 0, 0);
                const short* gq = W + (long)(bn + row) * ldw + kv + cg;
                __builtin_amdgcn_global_load_lds(
                    (const __attribute__((address_space(1))) void*)gq,
                    (__attribute__((address_space(3))) void*)(Ws + c * 8), 16, 0, 0);
            }
            __syncthreads();
#pragma unroll
            for (int kk = 0; kk < 2; ++kk) {
                short8 af[2], bfr[4];
#pragma unroll
                for (int mi = 0; mi < 2; ++mi) {
                    int r = wm + mi * 16 + lrow;
                    af[mi] = *(const short8*)(As + r * 64 +
                                              (((kk * 4 + quad) ^ (r & 7)) * 8));
                }
#pragma unroll
                for (int ni = 0; ni < 4; ++ni) {
                    int r = wn + ni * 16 + lrow;
                    bfr[ni] = *(const short8*)(Ws + r * 64 +
                                               (((kk * 4 + quad) ^ (r & 7)) * 8));
                }
#pragma unroll
                for (int mi = 0; mi < 2; ++mi)
#pragma unroll
                    for (int ni = 0; ni < 4; ++ni)
                        acc[mi][ni] = __builtin_amdgcn_mfma_f32_16x16x32_bf16(
                            af[mi], bfr[ni], acc[mi][ni], 0, 0, 0);
            }
            __syncthreads();
        }
        // segment-1 window (empty loop if this split doesn't reach seg1)
        A = A1 + (long)z * sA1;
        W = W1 + (long)z * sW1;
        lda = lda1; ldw = ldw1;
        kb = ((kbeg > K0) ? kbeg : K0) - K0;
        ke = kend - K0;
    }

    float* Cz = C + (long)z * sC + (long)s * sSplit;
#pragma unroll
    for (int mi = 0; mi < 2; ++mi)
#pragma unroll
        for (int ni = 0; ni < 4; ++ni)
#pragma unroll
            for (int r = 0; r < 4; ++r) {
                int row = bm + wm + mi * 16 + quad * 4 + r;
                int col = bn + wn + ni * 16 + lrow;
                Cz[(long)row * ldc + col] = acc[mi][ni][r];
            }
}

// ---------------------------------------------------------------------------
// gemm64: small GEMMs (gates, ogate). r4-proven: BK=64 + XOR swizzle,
// tile 64x128, 4 waves, bf16 out.
// ---------------------------------------------------------------------------
__global__ __launch_bounds__(256) void gemm64(
    const short* __restrict__ A0, int lda0, long sA0, int K0,
    const short* __restrict__ W0, int ldw0, long sW0,
    short* __restrict__ C, int ldc, long sC)
{
    __shared__ short As[64 * 64];
    __shared__ short Ws[128 * 64];
    const int t = threadIdx.x;
    const int z = blockIdx.z;
    const int bm = blockIdx.x * 64;
    const int bn = blockIdx.y * 128;
    const int lane = t & 63, w = t >> 6;
    const int wm = (w >> 1) * 32, wn = (w & 1) * 64;
    const int lrow = lane & 15, quad = lane >> 4;

    floatx4 acc[2][4] = {};

    const short* A = A0 + (long)z * sA0;
    const short* W = W0 + (long)z * sW0;

    for (int k0 = 0; k0 < K0; k0 += 64) {
#pragma unroll
        for (int i = 0; i < 2; ++i) {      // A: 64 rows x 8 chunks = 512
            int c = i * 256 + t;
            int row = c >> 3;
            int cg = ((c ^ row) & 7) * 8;
            const short* gp = A + (long)(bm + row) * lda0 + k0 + cg;
            __builtin_amdgcn_global_load_lds(
                (const __attribute__((address_space(1))) void*)gp,
                (__attribute__((address_space(3))) void*)(As + c * 8), 16, 0, 0);
        }
#pragma unroll
        for (int i = 0; i < 4; ++i) {      // W: 128 rows x 8 chunks = 1024
            int c = i * 256 + t;
            int row = c >> 3;
            int cg = ((c ^ row) & 7) * 8;
            const short* gq = W + (long)(bn + row) * ldw0 + k0 + cg;
            __builtin_amdgcn_global_load_lds(
                (const __attribute__((address_space(1))) void*)gq,
                (__attribute__((address_space(3))) void*)(Ws + c * 8), 16, 0, 0);
        }
        __syncthreads();
#pragma unroll
        for (int kk = 0; kk < 2; ++kk) {
            short8 af[2], bfr[4];
#pragma unroll
            for (int mi = 0; mi < 2; ++mi) {
                int r = wm + mi * 16 + lrow;
                af[mi] = *(const short8*)(As + r * 64 +
                                          (((kk * 4 + quad) ^ (r & 7)) * 8));
            }
#pragma unroll
            for (int ni = 0; ni < 4; ++ni) {
                int r = wn + ni * 16 + lrow;
                bfr[ni] = *(const short8*)(Ws + r * 64 +
                                           (((kk * 4 + quad) ^ (r & 7)) * 8));
            }
#pragma unroll
            for (int mi = 0; mi < 2; ++mi)
#pragma unroll
                for (int ni = 0; ni < 4; ++ni)
                    acc[mi][ni] = __builtin_amdgcn_mfma_f32_16x16x32_bf16(
                        af[mi], bfr[kk ? ni : ni], acc[mi][ni], 0, 0, 0);
        }
        __syncthreads();
    }

    short* Cz = C + (long)z * sC;
#pragma unroll
    for (int mi = 0; mi < 2; ++mi)
#pragma unroll
        for (int ni = 0; ni < 4; ++ni)
#pragma unroll
            for (int r = 0; r < 4; ++r) {
                int row = bm + wm + mi * 16 + quad * 4 + r;
                int col = bn + wn + ni * 16 + lrow;
                Cz[(long)row * ldc + col] = f2bf(acc[mi][ni][r]);
            }
}

// ---------------------------------------------------------------------------
// megapack8: all weight fp32->bf16 packs, 8 elems/thread. grid 13440 x 256
// ---------------------------------------------------------------------------
__global__ __launch_bounds__(256) void megapack8(
    const float* __restrict__ wx_b, const float* __restrict__ wx_s,
    const float* __restrict__ wh_b, const float* __restrict__ wh_s,
    const float* __restrict__ hz_b, const float* __restrict__ hz_s,
    const float* __restrict__ phi_b, const float* __restrict__ phi_s,
    const float* __restrict__ hh_w, const float* __restrict__ o_w,
    const float* __restrict__ f_w, const float* __restrict__ i_w,
    const float* __restrict__ g_w,
    short* __restrict__ Wx, short* __restrict__ Wh, short* __restrict__ Whz,
    short* __restrict__ Wphi, short* __restrict__ HHb, short* __restrict__ OWb,
    short* __restrict__ Wg)
{
    int bid = blockIdx.x, tid = threadIdx.x;
    const float* sp;
    short* dst;
    long e;
    if (bid < 1728) {                        // Wx: (1536, 2304) kan-pack
        e = ((long)bid * 256 + tid) * 8;
        int r = (int)(e / 2304), c = (int)(e % 2304);
        sp = (c < 256) ? wx_b + (long)r * 256 + c
                       : wx_s + (long)r * 2048 + (c - 256);
        dst = Wx + e;
    } else if (bid < 12096) {                // Wh/Whz/Wphi: (1536, 4608) each
        int jb = bid - 1728;
        int job = jb / 3456, lb = jb % 3456;
        const float* bp = (job == 0) ? wh_b : (job == 1) ? hz_b : phi_b;
        const float* spw = (job == 0) ? wh_s : (job == 1) ? hz_s : phi_s;
        short* dp = (job == 0) ? Wh : (job == 1) ? Whz : Wphi;
        e = ((long)lb * 256 + tid) * 8;
        int r = (int)(e / 4608), c = (int)(e % 4608);
        sp = (c < 512) ? bp + (long)r * 512 + c
                       : spw + (long)r * 4096 + (c - 512);
        dst = dp + e;
    } else if (bid < 12480) {                // hh_w flat 786432
        e = ((long)(bid - 12096) * 256 + tid) * 8;
        sp = hh_w + e; dst = HHb + e;
    } else if (bid < 12864) {                // o_w flat 786432
        e = ((long)(bid - 12480) * 256 + tid) * 8;
        sp = o_w + e; dst = OWb + e;
    } else if (bid < 13056) {                // f_w flat 393216
        e = ((long)(bid - 12864) * 256 + tid) * 8;
        sp = f_w + e; dst = Wg + e;
    } else if (bid < 13248) {                // i_w
        e = ((long)(bid - 13056) * 256 + tid) * 8;
        sp = i_w + e; dst = Wg + 393216 + e;
    } else {                                 // g_w
        e = ((long)(bid - 13248) * 256 + tid) * 8;
        sp = g_w + e; dst = Wg + 786432 + e;
    }
    float4 a = *(const float4*)sp;
    float4 b = *(const float4*)(sp + 4);
    short8 o;
    o[0] = f2bf(a.x); o[1] = f2bf(a.y); o[2] = f2bf(a.z); o[3] = f2bf(a.w);
    o[4] = f2bf(b.x); o[5] = f2bf(b.y); o[6] = f2bf(b.z); o[7] = f2bf(b.w);
    *(short8*)dst = o;
}

// ---------------------------------------------------------------------------
// prep_acts4: 4 elems/thread. grid: 9216 blocks x 256
// ---------------------------------------------------------------------------
__global__ __launch_bounds__(256) void prep_acts4(
    const float* __restrict__ x_t, const float* __restrict__ h_prev,
    const float* __restrict__ z_prev,
    short* __restrict__ Xe, short* __restrict__ Agate,
    short* __restrict__ Ze, short* __restrict__ zraw)
{
    int bid = blockIdx.x, tid = threadIdx.x;
    if (bid < 1024) {                        // x: 4 rows/block, 64 thr/row
        int r = (bid << 2) + (tid >> 6);
        int i = (tid & 63) << 2;
        float4 v = *(const float4*)(x_t + (long)r * 256 + i);
        *(short4v*)(Agate + (long)r * 768 + i) = pack4(v);
        long ob = (long)r * 2304;
        expand4(v, Xe + ob + i, Xe + ob + 256 + (long)i * 8);
    } else if (bid < 3072) {                 // h cast: flat
        long idx = ((long)(bid - 1024) * 256 + tid) * 4;
        float4 v = *(const float4*)(h_prev + idx);
        long b = idx >> 9; int hh = (int)(idx & 511);
        *(short4v*)(Agate + b * 768 + 256 + hh) = pack4(v);
    } else {                                 // z: 2 rows/block, 128 thr/row
        int jz = bid - 3072;
        int r = (jz << 1) + (tid >> 7);
        int i = (tid & 127) << 2;
        float4 v = *(const float4*)(z_prev + (long)r * 512 + i);
        *(short4v*)(zraw + (long)r * 512 + i) = pack4(v);
        long ob = (long)r * 4608;
        expand4(v, Ze + ob + i, Ze + ob + 512 + (long)i * 8);
    }
}

// ---------------------------------------------------------------------------
// expand_pair4: v = sum_s P[idx + s*sSplit]; silu+spline expand; optional
// bf16 compact. 4 elems/thread, 2 rows/block. grid: 6144 blocks x 256
// ---------------------------------------------------------------------------
__global__ __launch_bounds__(256) void expand_pair4(
    const float* __restrict__ P, long sSplit, int S,
    short* __restrict__ out, short* __restrict__ compact)
{
    int tid = threadIdx.x;
    int r = (blockIdx.x << 1) + (tid >> 7);
    int i = (tid & 127) << 2;
    long idx = (long)r * 512 + i;
    float4 v = *(const float4*)(P + idx);
    for (int s = 1; s < S; ++s) {
        float4 a = *(const float4*)(P + idx + (long)s * sSplit);
        v.x += a.x; v.y += a.y; v.z += a.z; v.w += a.w;
    }
    if (compact) *(short4v*)(compact + idx) = pack4(v);
    long ob = (long)r * 4608;
    expand4(v, out + ob + i, out + ob + 512 + (long)i * 8);
}

// ---------------------------------------------------------------------------
// ln_wave: LayerNorm rows of 512, one wave per row. grid: 3072 x 256
// ---------------------------------------------------------------------------
__global__ __launch_bounds__(256) void ln_wave(const float* __restrict__ P,
                                               long sSplit, int S,
                                               const float* __restrict__ hh_b,
                                               const float* __restrict__ ln_g,
                                               const float* __restrict__ ln_b,
                                               float* __restrict__ out)
{
    int wv = threadIdx.x >> 6, lane = threadIdx.x & 63;
    int row = blockIdx.x * 4 + wv;           // [0, 12288)
    int l = row >> 12;
    int col = lane * 8;
    long base = (long)row * 512 + col;
    float v[8];
#pragma unroll
    for (int e = 0; e < 8; ++e) v[e] = hh_b[l * 512 + col + e];
    for (int s = 0; s < S; ++s) {
        float4 a = *(const float4*)(P + base + (long)s * sSplit);
        float4 b = *(const float4*)(P + base + 4 + (long)s * sSplit);
        v[0] += a.x; v[1] += a.y; v[2] += a.z; v[3] += a.w;
        v[4] += b.x; v[5] += b.y; v[6] += b.z; v[7] += b.w;
    }
    float sm = 0.f, sq = 0.f;
#pragma unroll
    for (int e = 0; e < 8; ++e) { sm += v[e]; sq += v[e] * v[e]; }
#pragma unroll
    for (int off = 32; off; off >>= 1) {
        sm += __shfl_down(sm, off);
        sq += __shfl_down(sq, off);
    }
    sm = __shfl(sm, 0);
    sq = __shfl(sq, 0);
    float mu = sm * (1.f / 512.f);
    float var = sq * (1.f / 512.f) - mu * mu;
    float rstd = rsqrtf(var + 1e-5f);
    float o[8];
#pragma unroll
    for (int e = 0; e < 8; ++e)
        o[e] = (v[e] - mu) * rstd * ln_g[l * 512 + col + e] + ln_b[l * 512 + col + e];
    float* op = out + base;
    *(float4*)op = make_float4(o[0], o[1], o[2], o[3]);
    *(float4*)(op + 4) = make_float4(o[4], o[5], o[6], o[7]);
}

// final LSTM-style cell epilogue -> h_t, c_t
__global__ __launch_bounds__(256) void cell_epilogue(const short* __restrict__ gates,
                                                     const short* __restrict__ opre,
                                                     const float* __restrict__ c_prev,
                                                     const float* __restrict__ f_b,
                                                     const float* __restrict__ i_b,
                                                     const float* __restrict__ g_b,
                                                     const float* __restrict__ o_b,
                                                     float* __restrict__ out)
{
    long idx = blockIdx.x * 256L + threadIdx.x;
    long b = idx >> 9; int h = (int)(idx & 511);
    const short* g = gates + b * 1536;
    float fp = bf2f(g[h]) + f_b[h];
    float ip = bf2f(g[512 + h]) + i_b[h];
    float gp = bf2f(g[1024 + h]) + g_b[h];
    float op = bf2f(opre[idx]) + o_b[h];
    float ft = 1.f / (1.f + __expf(-fp));
    float it = 1.f / (1.f + __expf(-ip));
    float gt = tanhf(gp);
    float ot = 1.f / (1.f + __expf(-op));
    float c = ft * c_prev[idx] + it * gt;
    out[idx] = ot * tanhf(c);
    out[idx + 2097152] = c;
}

// ---------------------------------------------------------------------------
extern "C" void kernel_launch(void* const* d_in, const int* in_sizes, int n_in,
                              void* d_out, int out_size, void* d_ws, size_t ws_size,
                              hipStream_t stream)
{
    const float* x_t       = (const float*)d_in[0];
    const float* h_prev    = (const float*)d_in[1];
    const float* c_prev    = (const float*)d_in[2];
    const float* z_prev    = (const float*)d_in[3];
    const float* wx_base   = (const float*)d_in[4];
    const float* wx_spline = (const float*)d_in[5];
    const float* wh_base   = (const float*)d_in[6];
    const float* wh_spline = (const float*)d_in[7];
    const float* hz_base   = (const float*)d_in[8];
    const float* hz_spline = (const float*)d_in[9];
    const float* phi_base  = (const float*)d_in[10];
    const float* phi_spline= (const float*)d_in[11];
    const float* hh_w      = (const float*)d_in[12];
    const float* hh_b      = (const float*)d_in[13];
    const float* ln_g      = (const float*)d_in[14];
    const float* ln_b      = (const float*)d_in[15];
    const float* f_w       = (const float*)d_in[16];
    const float* f_b       = (const float*)d_in[17];
    const float* i_w       = (const float*)d_in[18];
    const float* i_b       = (const float*)d_in[19];
    const float* g_w       = (const float*)d_in[20];
    const float* g_b       = (const float*)d_in[21];
    const float* o_w       = (const float*)d_in[22];
    const float* o_b       = (const float*)d_in[23];
    float* out = (float*)d_out;
    const long BH = 4096L * 512;

    char* p = (char*)d_ws;
    auto alloc = [&](size_t bytes) {
        char* q = p;
        p += (bytes + 255) & ~(size_t)255;
        return q;
    };

    short* Wx   = (short*)alloc(3L * 512 * 2304 * 2);
    short* Wh   = (short*)alloc(3L * 512 * 4608 * 2);
    short* Whz  = (short*)alloc(3L * 512 * 4608 * 2);
    short* Wphi = (short*)alloc(3L * 512 * 4608 * 2);
    short* HHb  = (short*)alloc(3L * 512 * 512 * 2);
    short* OWb  = (short*)alloc(512L * 1536 * 2);
    short* Wg   = (short*)alloc(1536L * 768 * 2);
    short* Agate= (short*)alloc(4096L * 768 * 2);
    short* zraw = (short*)alloc(3L * 4096 * 512 * 2);
    short* XR   = (short*)alloc(4096L * 2304 * 2);      // Xe, later Rbuf
    short* Ebuf = (short*)alloc(3L * 4096 * 4608 * 2);  // Ze -> Se -> Oe -> gbuf/opre

    const int S = 2;                                    // split-K factor
    const long PS = 3L * 4096 * 512;                    // elems per split
    float* Pbuf = (float*)alloc((size_t)S * PS * 4);    // fp32 partials

    short* Xe = XR;
    short* Rbuf = XR;
    short* gbuf = Ebuf;
    short* opre = Ebuf + 4096L * 1536;

    // ---- all weight packing in one launch ----
    megapack8<<<13440, 256, 0, stream>>>(
        wx_base, wx_spline, wh_base, wh_spline, hz_base, hz_spline,
        phi_base, phi_spline, hh_w, o_w, f_w, i_w, g_w,
        Wx, Wh, Whz, Wphi, HHb, OWb, Wg);

    // ---- all activation prep in one launch ----
    prep_acts4<<<9216, 256, 0, stream>>>(x_t, h_prev, z_prev, Xe, Agate, Ebuf, zraw);

    // ---- s = Xe @ Wx^T + Ze @ Wh^T  (Ktot=6912, split 3456/3456) ----
    gemm128o<<<dim3(32, 4, 3 * S), 512, 0, stream>>>(S, 3456,
        Xe, 2304, 0L, 2304,              Wx, 2304, 512L * 2304,
        Ebuf, 4608, 4096L * 4608,        Wh, 4608, 512L * 4608,
        Pbuf, 512, 4096L * 512, PS);

    // ---- Se = expand(sum P) ----
    expand_pair4<<<6144, 256, 0, stream>>>(Pbuf, PS, S, Ebuf, (short*)0);

    // ---- o = Se @ Wphi^T (Ktot=4608, split 2304/2304) -> fp32 partials ----
    gemm128o<<<dim3(32, 4, 3 * S), 512, 0, stream>>>(S, 2304,
        Ebuf, 4608, 4096L * 4608, 4608,  Wphi, 4608, 512L * 4608,
        Ebuf, 4608, 4096L * 4608,        Wphi, 4608, 512L * 4608,
        Pbuf, 1536, 512, PS);

    // ---- Oe = expand(sum P); compact bf16 -> Rbuf ----
    expand_pair4<<<6144, 256, 0, stream>>>(Pbuf, PS, S, Ebuf, Rbuf);

    // ---- zpre = Oe @ Whz^T + zraw @ hh_w^T (Ktot=5120, split 2560/2560) ----
    gemm128o<<<dim3(32, 4, 3 * S), 512, 0, stream>>>(S, 2560,
        Ebuf, 13824, 4608, 4608,         Whz, 4608, 512L * 4608,
        zraw, 512, 4096L * 512,          HHb, 512, 512L * 512,
        Pbuf, 512, 4096L * 512, PS);

    // ---- z_all = LN(sum P + hh_b) ----
    ln_wave<<<3072, 256, 0, stream>>>(Pbuf, PS, S, hh_b, ln_g, ln_b, out + 2 * BH);

    // ---- gates (f,i,g) pre-activations (bf16 out) ----
    gemm64<<<dim3(64, 12, 1), 256, 0, stream>>>(
        Agate, 768, 0L, 768,  Wg, 768, 0L,
        gbuf, 1536, 0);

    // ---- output gate pre-activation (bf16 out) ----
    gemm64<<<dim3(64, 4, 1), 256, 0, stream>>>(
        Rbuf, 1536, 0L, 1536, OWb, 1536, 0L,
        opre, 512, 0);

    // ---- h_t, c_t ----
    cell_epilogue<<<8192, 256, 0, stream>>>(gbuf, opre, c_prev, f_b, i_b, g_b, o_b, out);
}